// Round 1
// baseline (136.559 us; speedup 1.0000x reference)
//
#include <hip/hip_runtime.h>
#include <math.h>

#define KEYS 11
#define NSTACK 4
#define NB 16
#define HH 128
#define WW 128
#define HW (HH * WW)

__global__ void kp_zero_out(float* out) {
    out[threadIdx.x] = 0.0f;  // 128 output floats
}

__global__ __launch_bounds__(256) void kp_loss_kernel(
    const float* __restrict__ cp,    // (16, 4, 22, 128, 128)
    const float* __restrict__ heat,  // (16, 11, 128, 128)
    const float* __restrict__ lab,   // (16, 11, 11)
    float* __restrict__ out)         // 128: heat_loss(64) then label_loss(64)
{
    const int bid = blockIdx.x;          // b*S*K + s*K + k
    const int k  = bid % KEYS;
    const int bs = bid / KEYS;           // b*NSTACK + s
    const int s  = bs % NSTACK;
    const int b  = bs / NSTACK;

    const float* __restrict__ hm = cp + ((size_t)((b * NSTACK + s) * (2 * KEYS) + k)) * HW;
    const float* __restrict__ ht = heat + ((size_t)(b * KEYS + k)) * HW;

    const int tid = threadIdx.x;
    float sum  = 0.0f;
    float vmax = -INFINITY;
    int   imax = 0;

    const float4* __restrict__ hm4 = (const float4*)hm;
    const float4* __restrict__ ht4 = (const float4*)ht;

    #pragma unroll 4
    for (int i = tid; i < HW / 4; i += 256) {
        float4 a = hm4[i];
        float4 c = ht4[i];
        float d0 = a.x - c.x, d1 = a.y - c.y, d2 = a.z - c.z, d3 = a.w - c.w;
        sum += d0 * d0 + d1 * d1 + d2 * d2 + d3 * d3;
        int base = i * 4;
        // strictly-greater keeps first occurrence (indices increase per thread)
        if (a.x > vmax) { vmax = a.x; imax = base;     }
        if (a.y > vmax) { vmax = a.y; imax = base + 1; }
        if (a.z > vmax) { vmax = a.z; imax = base + 2; }
        if (a.w > vmax) { vmax = a.w; imax = base + 3; }
    }

    // wave-64 reduction (sum + argmax with first-index tie break)
    #pragma unroll
    for (int off = 32; off > 0; off >>= 1) {
        float ov = __shfl_down(vmax, off);
        int   oi = __shfl_down(imax, off);
        float os = __shfl_down(sum,  off);
        sum += os;
        if (ov > vmax || (ov == vmax && oi < imax)) { vmax = ov; imax = oi; }
    }

    __shared__ float s_sum[4];
    __shared__ float s_v[4];
    __shared__ int   s_i[4];
    const int wave = tid >> 6;
    if ((tid & 63) == 0) { s_sum[wave] = sum; s_v[wave] = vmax; s_i[wave] = imax; }
    __syncthreads();

    if (tid == 0) {
        #pragma unroll
        for (int w = 1; w < 4; w++) {
            sum += s_sum[w];
            if (s_v[w] > vmax || (s_v[w] == vmax && s_i[w] < imax)) {
                vmax = s_v[w]; imax = s_i[w];
            }
        }
        atomicAdd(&out[bs], sum);

        // ---- label loss for this (b, s, k) ----
        const float* __restrict__ lb = cp + ((size_t)((b * NSTACK + s) * (2 * KEYS) + KEYS + k)) * HW;
        const float* __restrict__ L  = lab + (size_t)(b * KEYS + k) * 11;
        float gx = L[9], gy = L[10];
        bool valid = (gx > 0.0f) && (gy > 0.0f) && (gx < (float)HH) && (gy < (float)WW);
        if (valid) {
            float xf = (float)(imax / WW);   // row (x = index // m, m == W == 128)
            float yf = (float)(imax % WW);   // col
            float dx = gx + L[7] - xf - lb[7];
            float dy = gy + L[8] - yf - lb[8];
            float loss = dx * dx + dy * dy;
            float cm = 1.0f - vmax;
            loss += cm * cm;
            #pragma unroll
            for (int j = 0; j < 7; j++) {
                float d = lb[j] - L[j];
                loss += d * d;
            }
            atomicAdd(&out[64 + bs], loss);
        }
    }
}

extern "C" void kernel_launch(void* const* d_in, const int* in_sizes, int n_in,
                              void* d_out, int out_size, void* d_ws, size_t ws_size,
                              hipStream_t stream) {
    const float* cp   = (const float*)d_in[0];
    const float* heat = (const float*)d_in[1];
    const float* lab  = (const float*)d_in[2];
    float* out = (float*)d_out;

    kp_zero_out<<<1, 128, 0, stream>>>(out);
    kp_loss_kernel<<<NB * NSTACK * KEYS, 256, 0, stream>>>(cp, heat, lab, out);
}